// Round 6
// baseline (284.629 us; speedup 1.0000x reference)
//
#include <hip/hip_runtime.h>
#include <math.h>

#define F_IN  512
#define F_HID 256
#define F_OUT 64

typedef __attribute__((ext_vector_type(8))) short bf16x8;
typedef __attribute__((ext_vector_type(4))) short bf16x4;
typedef __attribute__((ext_vector_type(4))) float f32x4;

#define GLOBAL_AS __attribute__((address_space(1)))
#define LDS_AS    __attribute__((address_space(3)))

__device__ __forceinline__ void gload_lds16(const ushort* g, ushort* l) {
    __builtin_amdgcn_global_load_lds((const GLOBAL_AS uint32_t*)g,
                                     (LDS_AS uint32_t*)l, 16, 0, 0);
}

__device__ __forceinline__ ushort f2bf(float f) {
    union { float f; uint32_t u; } v; v.f = f;
    uint32_t r = (v.u + 0x7FFFu + ((v.u >> 16) & 1u)) >> 16;
    return (ushort)r;
}

__device__ __forceinline__ float bf2f(ushort u) {
    union { uint32_t u; float f; } v; v.u = ((uint32_t)u) << 16;
    return v.f;
}

// ---------------- degree ----------------
__global__ void k_deg(const int* __restrict__ dst, int* __restrict__ deg, int E) {
    int e = blockIdx.x * 256 + threadIdx.x;
    if (e < E) atomicAdd(&deg[dst[e]], 1);
}

// ---------------- scan level 1 (+ dinv fused) ----------------
__global__ void k_scan1(const int* __restrict__ deg, int* __restrict__ offs,
                        int* __restrict__ bsums, float* __restrict__ dinv, int N) {
    __shared__ int s[256];
    int tid = threadIdx.x;
    int i = blockIdx.x * 256 + tid;
    int v = (i < N) ? deg[i] : 0;
    if (i < N) dinv[i] = rsqrtf((float)(v + 1));   // +1 self loop
    s[tid] = v; __syncthreads();
    for (int d = 1; d < 256; d <<= 1) {
        int t = (tid >= d) ? s[tid - d] : 0;
        __syncthreads();
        s[tid] += t;
        __syncthreads();
    }
    if (i < N) offs[i] = s[tid] - v;
    if (tid == 255) bsums[blockIdx.x] = s[255];
}

__global__ void k_scan2(int* __restrict__ bsums, int n) {
    __shared__ int s[256];
    int tid = threadIdx.x;
    int v = (tid < n) ? bsums[tid] : 0;
    s[tid] = v; __syncthreads();
    for (int d = 1; d < 256; d <<= 1) {
        int t = (tid >= d) ? s[tid - d] : 0;
        __syncthreads();
        s[tid] += t;
        __syncthreads();
    }
    if (tid < n) bsums[tid] = s[tid] - v;
}

__global__ void k_scan3(int* __restrict__ offs, const int* __restrict__ bsums,
                        int* __restrict__ cursor, int2* __restrict__ jw, int N, int E) {
    int i = blockIdx.x * 256 + threadIdx.x;
    if (i < N) {
        int o = offs[i] + bsums[i >> 8];
        offs[i] = o;
        cursor[i] = o;
    }
    if (i == 0) offs[N] = E;
    if (i < 16) jw[E + i] = make_int2(0, 0);   // pad: row 0, weight 0
}

// fill packed (src_index, dinv[src]) per CSR slot
__global__ void k_fill(const int* __restrict__ src, const int* __restrict__ dst,
                       int* __restrict__ cursor, int2* __restrict__ jw,
                       const float* __restrict__ dinv, int E) {
    int e = blockIdx.x * 256 + threadIdx.x;
    if (e < E) {
        int s = src[e];
        int pos = atomicAdd(&cursor[dst[e]], 1);
        jw[pos] = make_int2(s, __float_as_int(dinv[s]));
    }
}

// ---------------- weight transpose-casts (W1 and W2 in one launch) ----------------
// W1: [512][256] fp32 -> w1t [256][512] bf16 ; W2: [256][64] fp32 -> w2t [64][256] bf16
__global__ void k_tcast2(const float* __restrict__ W1, ushort* __restrict__ w1t,
                         const float* __restrict__ W2, ushort* __restrict__ w2t) {
    int idx = blockIdx.x * 256 + threadIdx.x;
    const int n1 = F_IN * F_HID;
    if (idx < n1) {
        int n = idx / F_IN, k = idx - n * F_IN;
        w1t[idx] = f2bf(W1[(size_t)k * F_HID + n]);
    } else {
        int t = idx - n1;
        if (t < F_HID * F_OUT) {
            int n = t / F_HID, k = t - n * F_HID;
            w2t[t] = f2bf(W2[(size_t)k * F_OUT + n]);
        }
    }
}

// ---------------- fused GEMM1: h1[M,256] = bf16( fp32 x[M,512] @ W1 ) ----------------
// BM=64, BN=256 (grid.x covers M only -> x read exactly once), BK=32, 4 waves.
// A: reg-staged fp32->bf16 into padded LDS [64][40]. B: global_load_lds, chunked [4][257*8].
__global__ __launch_bounds__(256) void k_gemm1_fused(
        const float* __restrict__ A, const ushort* __restrict__ Bt,
        ushort* __restrict__ C, int M) {
    constexpr int K = F_IN, Nc = F_HID, BM = 64;
    constexpr int ASTR = 40;                  // padded row stride (ushorts)
    constexpr int BCH = 257 * 8;              // chunk stride (ushorts)
    __shared__ ushort As[BM * ASTR];
    __shared__ ushort Bs[4 * BCH];
    const int tid  = threadIdx.x;
    const int wave = tid >> 6, lane = tid & 63;
    const int brow = blockIdx.x * BM;

    f32x4 acc[4][4];
    #pragma unroll
    for (int m = 0; m < 4; ++m)
        #pragma unroll
        for (int n = 0; n < 4; ++n) acc[m][n] = (f32x4){0.f, 0.f, 0.f, 0.f};

    // A staging map: 4 threads per row, 8 fp32 each
    const int arow = tid >> 2;
    const int akc  = (tid & 3) * 8;
    int agrow = brow + arow; if (agrow >= M) agrow = M - 1;
    const float* aptr = &A[(size_t)agrow * K + akc];

    const int kq  = (lane >> 4) * 8;
    const int rA0 = lane & 15;
    const int cF  = wave * 64 + (lane & 15);  // this lane's fragment column base

    for (int k0 = 0; k0 < K; k0 += 32) {
        // --- A: load fp32, convert, ds_write ---
        float4 v0 = *(const float4*)(aptr + k0);
        float4 v1 = *(const float4*)(aptr + k0 + 4);
        bf16x8 av;
        av[0] = (short)f2bf(v0.x); av[1] = (short)f2bf(v0.y);
        av[2] = (short)f2bf(v0.z); av[3] = (short)f2bf(v0.w);
        av[4] = (short)f2bf(v1.x); av[5] = (short)f2bf(v1.y);
        av[6] = (short)f2bf(v1.z); av[7] = (short)f2bf(v1.w);
        *(bf16x8*)&As[arow * ASTR + akc] = av;
        // --- B: 4 async 1KB loads per wave; instr m covers chunk c, row-group rg ---
        #pragma unroll
        for (int l = 0; l < 4; ++l) {
            int m_ = wave * 4 + l;
            int c = m_ & 3, rg = m_ >> 2;
            gload_lds16(&Bt[(size_t)(rg * 64 + lane) * K + k0 + c * 8],
                        &Bs[c * BCH + rg * 64 * 8]);
        }
        __syncthreads();
        bf16x8 af[4], bfr[4];
        #pragma unroll
        for (int m = 0; m < 4; ++m)
            af[m] = *(const bf16x8*)&As[(rA0 + m * 16) * ASTR + kq];
        #pragma unroll
        for (int n = 0; n < 4; ++n)
            bfr[n] = *(const bf16x8*)&Bs[(lane >> 4) * BCH + (cF + n * 16) * 8];
        #pragma unroll
        for (int m = 0; m < 4; ++m)
            #pragma unroll
            for (int n = 0; n < 4; ++n)
                acc[m][n] = __builtin_amdgcn_mfma_f32_16x16x32_bf16(af[m], bfr[n], acc[m][n], 0, 0, 0);
        __syncthreads();
    }

    const int crow0 = brow + (lane >> 4) * 4;
    const int ccol0 = wave * 64 + (lane & 15);
    #pragma unroll
    for (int m = 0; m < 4; ++m)
        #pragma unroll
        for (int n = 0; n < 4; ++n)
            #pragma unroll
            for (int j = 0; j < 4; ++j) {
                int row = crow0 + m * 16 + j;
                if (row < M) C[(size_t)row * Nc + ccol0 + n * 16] = f2bf(acc[m][n][j]);
            }
}

// ---------------- bf16 MFMA GEMM2: C[M,64] = A[M,256] @ Bt[64,256]^T (bf16 out) ----------------
template<int WR, int WC, int MR, int NR>
__global__ __launch_bounds__(256) void k_gemm_bf16(
        const ushort* __restrict__ A, const ushort* __restrict__ Bt,
        ushort* __restrict__ C, int M, int K, int Nc) {
    constexpr int BM = WR * MR * 16;
    constexpr int BN = WC * NR * 16;
    __shared__ ushort As[BM * 32];
    __shared__ ushort Bs[BN * 32];
    const int tid  = threadIdx.x;
    const int wave = tid >> 6, lane = tid & 63;
    const int wr = wave % WR, wc = wave / WR;
    const int brow = blockIdx.y * BM, bcol = blockIdx.x * BN;

    f32x4 acc[MR][NR];
    #pragma unroll
    for (int m = 0; m < MR; ++m)
        #pragma unroll
        for (int n = 0; n < NR; ++n) acc[m][n] = (f32x4){0.f, 0.f, 0.f, 0.f};

    const int srow = tid >> 2;
    const int scol = (tid & 3) * 8;
    const int kq  = (lane >> 4) * 8;
    const int rA0 = wr * MR * 16 + (lane & 15);
    const int rB0 = wc * NR * 16 + (lane & 15);

    for (int k0 = 0; k0 < K; k0 += 32) {
        #pragma unroll
        for (int l = 0; l < BM / 64; ++l) {
            int row = brow + l * 64 + srow;
            if (row >= M) row = M - 1;
            gload_lds16(&A[(size_t)row * K + k0 + scol], &As[l * 2048 + wave * 512]);
        }
        #pragma unroll
        for (int l = 0; l < BN / 64; ++l) {
            int row = bcol + l * 64 + srow;
            gload_lds16(&Bt[(size_t)row * K + k0 + scol], &Bs[l * 2048 + wave * 512]);
        }
        __syncthreads();
        bf16x8 af[MR], bfr[NR];
        #pragma unroll
        for (int m = 0; m < MR; ++m)
            af[m] = *(const bf16x8*)&As[(rA0 + m * 16) * 32 + kq];
        #pragma unroll
        for (int n = 0; n < NR; ++n)
            bfr[n] = *(const bf16x8*)&Bs[(rB0 + n * 16) * 32 + kq];
        #pragma unroll
        for (int m = 0; m < MR; ++m)
            #pragma unroll
            for (int n = 0; n < NR; ++n)
                acc[m][n] = __builtin_amdgcn_mfma_f32_16x16x32_bf16(af[m], bfr[n], acc[m][n], 0, 0, 0);
        __syncthreads();
    }

    const int crow0 = brow + wr * MR * 16 + (lane >> 4) * 4;
    const int ccol0 = bcol + wc * NR * 16 + (lane & 15);
    #pragma unroll
    for (int m = 0; m < MR; ++m)
        #pragma unroll
        for (int n = 0; n < NR; ++n)
            #pragma unroll
            for (int j = 0; j < 4; ++j) {
                int row = crow0 + m * 16 + j;
                if (row < M) C[(size_t)row * Nc + ccol0 + n * 16] = f2bf(acc[m][n][j]);
            }
}

// ---------------- layer-1 aggregation: paired-row gathers ----------------
// lane = (feature group g = lane&31 owning 8 features, edge parity p = lane>>5).
// One bf16x8 load gathers 16B/lane -> two h-rows (1KB) per instruction.
__global__ __launch_bounds__(256) void k_agg1(
        const ushort* __restrict__ h, const int2* __restrict__ jw,
        const int* __restrict__ offs, const float* __restrict__ dinv,
        const float* __restrict__ bias, ushort* __restrict__ outm, int N) {
    int wave = threadIdx.x >> 6, lane = threadIdx.x & 63;
    int i = blockIdx.x * 4 + wave;
    if (i >= N) return;
    int g = lane & 31;        // features g*8 .. g*8+7
    int p = lane >> 5;        // edge parity
    float di = dinv[i];
    float acc[8];
    {
        bf16x8 hv = *(const bf16x8*)&h[(size_t)i * F_HID + g * 8];
        float w = (p == 0) ? di * di : 0.f;     // self loop counted once
        #pragma unroll
        for (int k = 0; k < 8; ++k) acc[k] = bf2f((ushort)hv[k]) * w;
    }
    int s = offs[i], e = offs[i + 1];
    for (int u = s; u < e; u += 12) {
        int2 a[6];
        #pragma unroll
        for (int q = 0; q < 6; ++q) a[q] = jw[u + 2 * q + p];   // overrun -> pad/next-node, masked
        bf16x8 hv[6];
        #pragma unroll
        for (int q = 0; q < 6; ++q)
            hv[q] = *(const bf16x8*)&h[(size_t)a[q].x * F_HID + g * 8];
        #pragma unroll
        for (int q = 0; q < 6; ++q) {
            float ww = (u + 2 * q + p < e) ? __int_as_float(a[q].y) * di : 0.f;
            #pragma unroll
            for (int k = 0; k < 8; ++k) acc[k] += bf2f((ushort)hv[q][k]) * ww;
        }
    }
    #pragma unroll
    for (int k = 0; k < 8; ++k) acc[k] += __shfl_xor(acc[k], 32, 64);
    if (p == 0) {
        float4 b0 = *(const float4*)&bias[g * 8];
        float4 b1 = *(const float4*)&bias[g * 8 + 4];
        bf16x8 o;
        o[0] = (short)f2bf(fmaxf(acc[0] + b0.x, 0.f));
        o[1] = (short)f2bf(fmaxf(acc[1] + b0.y, 0.f));
        o[2] = (short)f2bf(fmaxf(acc[2] + b0.z, 0.f));
        o[3] = (short)f2bf(fmaxf(acc[3] + b0.w, 0.f));
        o[4] = (short)f2bf(fmaxf(acc[4] + b1.x, 0.f));
        o[5] = (short)f2bf(fmaxf(acc[5] + b1.y, 0.f));
        o[6] = (short)f2bf(fmaxf(acc[6] + b1.z, 0.f));
        o[7] = (short)f2bf(fmaxf(acc[7] + b1.w, 0.f));
        *(bf16x8*)&outm[(size_t)i * F_HID + g * 8] = o;
    }
}

// ---------------- layer-2 aggregation + bias + log_softmax: wave per node, 16-unroll ----------------
__global__ __launch_bounds__(256) void k_agg2(
        const ushort* __restrict__ h, const int2* __restrict__ jw,
        const int* __restrict__ offs, const float* __restrict__ dinv,
        const float* __restrict__ bias, float* __restrict__ outm, int N) {
    int wave = threadIdx.x >> 6, lane = threadIdx.x & 63;
    int i = blockIdx.x * 4 + wave;
    if (i >= N) return;
    float di = dinv[i];
    float acc = bf2f(h[(size_t)i * F_OUT + lane]) * di * di;
    int s = offs[i], e = offs[i + 1];
    for (int u = s; u < e; u += 16) {
        int2 a[16];
        #pragma unroll
        for (int q = 0; q < 16; ++q) a[q] = jw[u + q];
        float hv[16];
        #pragma unroll
        for (int q = 0; q < 16; ++q)
            hv[q] = bf2f(h[(size_t)a[q].x * F_OUT + lane]);
        #pragma unroll
        for (int q = 0; q < 16; ++q) {
            float ww = (u + q < e) ? __int_as_float(a[q].y) * di : 0.f;
            acc += hv[q] * ww;
        }
    }
    acc += bias[lane];
    float m = acc;
    #pragma unroll
    for (int o = 32; o >= 1; o >>= 1) m = fmaxf(m, __shfl_xor(m, o, 64));
    float ex = expf(acc - m);
    float ssum = ex;
    #pragma unroll
    for (int o = 32; o >= 1; o >>= 1) ssum += __shfl_xor(ssum, o, 64);
    outm[(size_t)i * F_OUT + lane] = acc - m - logf(ssum);
}

extern "C" void kernel_launch(void* const* d_in, const int* in_sizes, int n_in,
                              void* d_out, int out_size, void* d_ws, size_t ws_size,
                              hipStream_t stream) {
    const float* x  = (const float*)d_in[0];
    const int*   ei = (const int*)d_in[1];
    const float* W1 = (const float*)d_in[2];
    const float* b1 = (const float*)d_in[3];
    const float* W2 = (const float*)d_in[4];
    const float* b2 = (const float*)d_in[5];
    float* out = (float*)d_out;

    int N = in_sizes[0] / F_IN;   // 50000
    int E = in_sizes[1] / 2;      // 800000
    const int* src = ei;
    const int* dst = ei + E;

    // workspace layout (16B aligned by construction)
    ushort* w1t = (ushort*)d_ws;                        // 256*512
    ushort* w2t = w1t + F_HID * F_IN;                   // 64*256
    ushort* h1  = w2t + F_OUT * F_HID;                  // N*256 bf16
    ushort* a1  = h1 + (size_t)N * F_HID;               // N*256 bf16
    int*    deg = (int*)(a1 + (size_t)N * F_HID);       // N
    float*  dinv = (float*)(deg + N);                   // N
    int*    offs = (int*)(dinv + N);                    // N+1
    int*    cursor = offs + N + 1;                      // N
    int*    bsums  = cursor + N;                        // 256
    int2*   jw = (int2*)(((uintptr_t)(bsums + 256) + 7) & ~(uintptr_t)7);  // E+16
    ushort* h2 = h1;     // alias: h1 dead after agg1

    int nch = (N + 255) / 256;

    hipMemsetAsync(deg, 0, sizeof(int) * N, stream);
    k_deg <<<(E + 255) / 256, 256, 0, stream>>>(dst, deg, E);
    k_scan1<<<nch, 256, 0, stream>>>(deg, offs, bsums, dinv, N);
    k_scan2<<<1, 256, 0, stream>>>(bsums, nch);
    k_scan3<<<nch, 256, 0, stream>>>(offs, bsums, cursor, jw, N, E);
    k_fill<<<(E + 255) / 256, 256, 0, stream>>>(src, dst, cursor, jw, dinv, E);

    // weight transpose-casts (one launch)
    int ntc = F_IN * F_HID + F_HID * F_OUT;
    k_tcast2<<<(ntc + 255) / 256, 256, 0, stream>>>(W1, w1t, W2, w2t);

    // layer 1: fused cast+GEMM (x fp32 read once) + paired-gather aggregate
    k_gemm1_fused<<<(N + 63) / 64, 256, 0, stream>>>(x, w1t, h1, N);
    k_agg1<<<(N + 3) / 4, 256, 0, stream>>>(h1, jw, offs, dinv, b1, a1, N);

    // layer 2: GEMM (BM=128, BN=64, A read once) + aggregate + log_softmax
    k_gemm_bf16<4, 1, 2, 4><<<dim3(1, (N + 127) / 128), 256, 0, stream>>>(
        a1, w2t, h2, N, F_HID, F_OUT);
    k_agg2<<<(N + 3) / 4, 256, 0, stream>>>(h2, jw, offs, dinv, b2, out, N);
}

// Round 7
// 262.116 us; speedup vs baseline: 1.0859x; 1.0859x over previous
//
#include <hip/hip_runtime.h>
#include <math.h>

#define F_IN  512
#define F_HID 256
#define F_OUT 64

typedef __attribute__((ext_vector_type(8))) short bf16x8;
typedef __attribute__((ext_vector_type(4))) short bf16x4;
typedef __attribute__((ext_vector_type(4))) float f32x4;

#define GLOBAL_AS __attribute__((address_space(1)))
#define LDS_AS    __attribute__((address_space(3)))

__device__ __forceinline__ void gload_lds16(const ushort* g, ushort* l) {
    __builtin_amdgcn_global_load_lds((const GLOBAL_AS uint32_t*)g,
                                     (LDS_AS uint32_t*)l, 16, 0, 0);
}

__device__ __forceinline__ ushort f2bf(float f) {
    union { float f; uint32_t u; } v; v.f = f;
    uint32_t r = (v.u + 0x7FFFu + ((v.u >> 16) & 1u)) >> 16;
    return (ushort)r;
}

__device__ __forceinline__ float bf2f(ushort u) {
    union { uint32_t u; float f; } v; v.u = ((uint32_t)u) << 16;
    return v.f;
}

// ---------------- degree ----------------
__global__ void k_deg(const int* __restrict__ dst, int* __restrict__ deg, int E) {
    int e = blockIdx.x * 256 + threadIdx.x;
    if (e < E) atomicAdd(&deg[dst[e]], 1);
}

// ---------------- scan level 1 (+ dinv fused) ----------------
__global__ void k_scan1(const int* __restrict__ deg, int* __restrict__ offs,
                        int* __restrict__ bsums, float* __restrict__ dinv, int N) {
    __shared__ int s[256];
    int tid = threadIdx.x;
    int i = blockIdx.x * 256 + tid;
    int v = (i < N) ? deg[i] : 0;
    if (i < N) dinv[i] = rsqrtf((float)(v + 1));   // +1 self loop
    s[tid] = v; __syncthreads();
    for (int d = 1; d < 256; d <<= 1) {
        int t = (tid >= d) ? s[tid - d] : 0;
        __syncthreads();
        s[tid] += t;
        __syncthreads();
    }
    if (i < N) offs[i] = s[tid] - v;
    if (tid == 255) bsums[blockIdx.x] = s[255];
}

__global__ void k_scan2(int* __restrict__ bsums, int n) {
    __shared__ int s[256];
    int tid = threadIdx.x;
    int v = (tid < n) ? bsums[tid] : 0;
    s[tid] = v; __syncthreads();
    for (int d = 1; d < 256; d <<= 1) {
        int t = (tid >= d) ? s[tid - d] : 0;
        __syncthreads();
        s[tid] += t;
        __syncthreads();
    }
    if (tid < n) bsums[tid] = s[tid] - v;
}

__global__ void k_scan3(int* __restrict__ offs, const int* __restrict__ bsums,
                        int* __restrict__ cursor, int2* __restrict__ jw, int N, int E) {
    int i = blockIdx.x * 256 + threadIdx.x;
    if (i < N) {
        int o = offs[i] + bsums[i >> 8];
        offs[i] = o;
        cursor[i] = o;
    }
    if (i == 0) offs[N] = E;
    if (i < 16) jw[E + i] = make_int2(0, 0);   // pad: row 0, weight 0
}

// fill packed (src_index, dinv[src]) per CSR slot
__global__ void k_fill(const int* __restrict__ src, const int* __restrict__ dst,
                       int* __restrict__ cursor, int2* __restrict__ jw,
                       const float* __restrict__ dinv, int E) {
    int e = blockIdx.x * 256 + threadIdx.x;
    if (e < E) {
        int s = src[e];
        int pos = atomicAdd(&cursor[dst[e]], 1);
        jw[pos] = make_int2(s, __float_as_int(dinv[s]));
    }
}

// ---------------- weight transpose-casts (W1 and W2 in one launch) ----------------
__global__ void k_tcast2(const float* __restrict__ W1, ushort* __restrict__ w1t,
                         const float* __restrict__ W2, ushort* __restrict__ w2t) {
    int idx = blockIdx.x * 256 + threadIdx.x;
    const int n1 = F_IN * F_HID;
    if (idx < n1) {
        int n = idx / F_IN, k = idx - n * F_IN;
        w1t[idx] = f2bf(W1[(size_t)k * F_HID + n]);
    } else {
        int t = idx - n1;
        if (t < F_HID * F_OUT) {
            int n = t / F_HID, k = t - n * F_HID;
            w2t[t] = f2bf(W2[(size_t)k * F_OUT + n]);
        }
    }
}

// ---------------- GEMM1: h1[M,256] = bf16( fp32 x[M,512] @ w1t^T ) ----------------
// 128x128 tile, BK=32, 4 waves (WR=WC=2, MR=NR=4). A reg-staged fp32->bf16 with
// next-step prefetch; As padded stride 36 (conflict-free A-frag reads).
// B via coalesced global_load_lds (linear [128][32]).
__global__ __launch_bounds__(256) void k_gemm1(
        const float* __restrict__ A, const ushort* __restrict__ Bt,
        ushort* __restrict__ C, int M) {
    constexpr int K = F_IN, Nc = F_HID, BM = 128, BN = 128;
    constexpr int ASTR = 36;
    __shared__ ushort As[BM * ASTR];
    __shared__ ushort Bs[BN * 32];
    const int tid  = threadIdx.x;
    const int wave = tid >> 6, lane = tid & 63;
    const int wr = wave & 1, wc = wave >> 1;
    const int brow = blockIdx.y * BM, bcol = blockIdx.x * BN;

    f32x4 acc[4][4];
    #pragma unroll
    for (int m = 0; m < 4; ++m)
        #pragma unroll
        for (int n = 0; n < 4; ++n) acc[m][n] = (f32x4){0.f, 0.f, 0.f, 0.f};

    // A stage map: 2 threads per row, 16 fp32 (64B) each
    const int arow = tid >> 1;
    const int akh  = (tid & 1) * 16;
    int agrow = brow + arow; if (agrow >= M) agrow = M - 1;
    const float4* aptr = (const float4*)&A[(size_t)agrow * K];
    // B stage map: 4 threads per row, 16B each (coalesced 64B per row-quad)
    const int srow = tid >> 2;
    const int scol = (tid & 3) * 8;

    const int kq  = (lane >> 4) * 8;
    const int rA0 = wr * 64 + (lane & 15);
    const int rB0 = wc * 64 + (lane & 15);

    float4 v0 = aptr[akh / 4 + 0], v1 = aptr[akh / 4 + 1],
           v2 = aptr[akh / 4 + 2], v3 = aptr[akh / 4 + 3];

    for (int k0 = 0; k0 < K; k0 += 32) {
        // convert prefetched A regs -> LDS
        bf16x8 a0, a1_;
        a0[0] = (short)f2bf(v0.x); a0[1] = (short)f2bf(v0.y);
        a0[2] = (short)f2bf(v0.z); a0[3] = (short)f2bf(v0.w);
        a0[4] = (short)f2bf(v1.x); a0[5] = (short)f2bf(v1.y);
        a0[6] = (short)f2bf(v1.z); a0[7] = (short)f2bf(v1.w);
        a1_[0] = (short)f2bf(v2.x); a1_[1] = (short)f2bf(v2.y);
        a1_[2] = (short)f2bf(v2.z); a1_[3] = (short)f2bf(v2.w);
        a1_[4] = (short)f2bf(v3.x); a1_[5] = (short)f2bf(v3.y);
        a1_[6] = (short)f2bf(v3.z); a1_[7] = (short)f2bf(v3.w);
        *(bf16x8*)&As[arow * ASTR + akh]     = a0;
        *(bf16x8*)&As[arow * ASTR + akh + 8] = a1_;
        // B: async staged, coalesced
        #pragma unroll
        for (int l = 0; l < 2; ++l)
            gload_lds16(&Bt[(size_t)(bcol + l * 64 + srow) * K + k0 + scol],
                        &Bs[l * 2048 + wave * 512]);
        __syncthreads();
        // prefetch next k-step's A (overlaps with ds_read + MFMA below)
        if (k0 + 32 < K) {
            int b = (k0 + 32 + akh) / 4;
            v0 = aptr[b]; v1 = aptr[b + 1]; v2 = aptr[b + 2]; v3 = aptr[b + 3];
        }
        bf16x8 af[4], bfr[4];
        #pragma unroll
        for (int m = 0; m < 4; ++m)
            af[m] = *(const bf16x8*)&As[(rA0 + m * 16) * ASTR + kq];
        #pragma unroll
        for (int n = 0; n < 4; ++n)
            bfr[n] = *(const bf16x8*)&Bs[(rB0 + n * 16) * 32 + kq];
        #pragma unroll
        for (int m = 0; m < 4; ++m)
            #pragma unroll
            for (int n = 0; n < 4; ++n)
                acc[m][n] = __builtin_amdgcn_mfma_f32_16x16x32_bf16(af[m], bfr[n], acc[m][n], 0, 0, 0);
        __syncthreads();
    }

    const int crow0 = brow + wr * 64 + (lane >> 4) * 4;
    const int ccol0 = bcol + wc * 64 + (lane & 15);
    #pragma unroll
    for (int m = 0; m < 4; ++m)
        #pragma unroll
        for (int n = 0; n < 4; ++n)
            #pragma unroll
            for (int j = 0; j < 4; ++j) {
                int row = crow0 + m * 16 + j;
                if (row < M) C[(size_t)row * Nc + ccol0 + n * 16] = f2bf(acc[m][n][j]);
            }
}

// ---------------- bf16 MFMA GEMM2: C[M,64] = A[M,256] @ Bt[64,256]^T (bf16 out) ----------------
template<int WR, int WC, int MR, int NR>
__global__ __launch_bounds__(256) void k_gemm_bf16(
        const ushort* __restrict__ A, const ushort* __restrict__ Bt,
        ushort* __restrict__ C, int M, int K, int Nc) {
    constexpr int BM = WR * MR * 16;
    constexpr int BN = WC * NR * 16;
    __shared__ ushort As[BM * 32];
    __shared__ ushort Bs[BN * 32];
    const int tid  = threadIdx.x;
    const int wave = tid >> 6, lane = tid & 63;
    const int wr = wave % WR, wc = wave / WR;
    const int brow = blockIdx.y * BM, bcol = blockIdx.x * BN;

    f32x4 acc[MR][NR];
    #pragma unroll
    for (int m = 0; m < MR; ++m)
        #pragma unroll
        for (int n = 0; n < NR; ++n) acc[m][n] = (f32x4){0.f, 0.f, 0.f, 0.f};

    const int srow = tid >> 2;
    const int scol = (tid & 3) * 8;
    const int kq  = (lane >> 4) * 8;
    const int rA0 = wr * MR * 16 + (lane & 15);
    const int rB0 = wc * NR * 16 + (lane & 15);

    for (int k0 = 0; k0 < K; k0 += 32) {
        #pragma unroll
        for (int l = 0; l < BM / 64; ++l) {
            int row = brow + l * 64 + srow;
            if (row >= M) row = M - 1;
            gload_lds16(&A[(size_t)row * K + k0 + scol], &As[l * 2048 + wave * 512]);
        }
        #pragma unroll
        for (int l = 0; l < BN / 64; ++l) {
            int row = bcol + l * 64 + srow;
            gload_lds16(&Bt[(size_t)row * K + k0 + scol], &Bs[l * 2048 + wave * 512]);
        }
        __syncthreads();
        bf16x8 af[MR], bfr[NR];
        #pragma unroll
        for (int m = 0; m < MR; ++m)
            af[m] = *(const bf16x8*)&As[(rA0 + m * 16) * 32 + kq];
        #pragma unroll
        for (int n = 0; n < NR; ++n)
            bfr[n] = *(const bf16x8*)&Bs[(rB0 + n * 16) * 32 + kq];
        #pragma unroll
        for (int m = 0; m < MR; ++m)
            #pragma unroll
            for (int n = 0; n < NR; ++n)
                acc[m][n] = __builtin_amdgcn_mfma_f32_16x16x32_bf16(af[m], bfr[n], acc[m][n], 0, 0, 0);
        __syncthreads();
    }

    const int crow0 = brow + wr * MR * 16 + (lane >> 4) * 4;
    const int ccol0 = bcol + wc * NR * 16 + (lane & 15);
    #pragma unroll
    for (int m = 0; m < MR; ++m)
        #pragma unroll
        for (int n = 0; n < NR; ++n)
            #pragma unroll
            for (int j = 0; j < 4; ++j) {
                int row = crow0 + m * 16 + j;
                if (row < M) C[(size_t)row * Nc + ccol0 + n * 16] = f2bf(acc[m][n][j]);
            }
}

// ---------------- layer-1 aggregation: paired-row gathers ----------------
__global__ __launch_bounds__(256) void k_agg1(
        const ushort* __restrict__ h, const int2* __restrict__ jw,
        const int* __restrict__ offs, const float* __restrict__ dinv,
        const float* __restrict__ bias, ushort* __restrict__ outm, int N) {
    int wave = threadIdx.x >> 6, lane = threadIdx.x & 63;
    int i = blockIdx.x * 4 + wave;
    if (i >= N) return;
    int g = lane & 31;        // features g*8 .. g*8+7
    int p = lane >> 5;        // edge parity
    float di = dinv[i];
    float acc[8];
    {
        bf16x8 hv = *(const bf16x8*)&h[(size_t)i * F_HID + g * 8];
        float w = (p == 0) ? di * di : 0.f;     // self loop counted once
        #pragma unroll
        for (int k = 0; k < 8; ++k) acc[k] = bf2f((ushort)hv[k]) * w;
    }
    int s = offs[i], e = offs[i + 1];
    for (int u = s; u < e; u += 12) {
        int2 a[6];
        #pragma unroll
        for (int q = 0; q < 6; ++q) a[q] = jw[u + 2 * q + p];   // overrun -> pad/next-node, masked
        bf16x8 hv[6];
        #pragma unroll
        for (int q = 0; q < 6; ++q)
            hv[q] = *(const bf16x8*)&h[(size_t)a[q].x * F_HID + g * 8];
        #pragma unroll
        for (int q = 0; q < 6; ++q) {
            float ww = (u + 2 * q + p < e) ? __int_as_float(a[q].y) * di : 0.f;
            #pragma unroll
            for (int k = 0; k < 8; ++k) acc[k] += bf2f((ushort)hv[q][k]) * ww;
        }
    }
    #pragma unroll
    for (int k = 0; k < 8; ++k) acc[k] += __shfl_xor(acc[k], 32, 64);
    if (p == 0) {
        float4 b0 = *(const float4*)&bias[g * 8];
        float4 b1 = *(const float4*)&bias[g * 8 + 4];
        bf16x8 o;
        o[0] = (short)f2bf(fmaxf(acc[0] + b0.x, 0.f));
        o[1] = (short)f2bf(fmaxf(acc[1] + b0.y, 0.f));
        o[2] = (short)f2bf(fmaxf(acc[2] + b0.z, 0.f));
        o[3] = (short)f2bf(fmaxf(acc[3] + b0.w, 0.f));
        o[4] = (short)f2bf(fmaxf(acc[4] + b1.x, 0.f));
        o[5] = (short)f2bf(fmaxf(acc[5] + b1.y, 0.f));
        o[6] = (short)f2bf(fmaxf(acc[6] + b1.z, 0.f));
        o[7] = (short)f2bf(fmaxf(acc[7] + b1.w, 0.f));
        *(bf16x8*)&outm[(size_t)i * F_HID + g * 8] = o;
    }
}

// ---------------- layer-2 aggregation + bias + log_softmax: wave per node, 8-unroll ----------------
__global__ __launch_bounds__(256) void k_agg2(
        const ushort* __restrict__ h, const int2* __restrict__ jw,
        const int* __restrict__ offs, const float* __restrict__ dinv,
        const float* __restrict__ bias, float* __restrict__ outm, int N) {
    int wave = threadIdx.x >> 6, lane = threadIdx.x & 63;
    int i = blockIdx.x * 4 + wave;
    if (i >= N) return;
    float di = dinv[i];
    float acc = bf2f(h[(size_t)i * F_OUT + lane]) * di * di;
    int s = offs[i], e = offs[i + 1];
    for (int u = s; u < e; u += 8) {
        int2 a[8];
        #pragma unroll
        for (int q = 0; q < 8; ++q) a[q] = jw[u + q];
        float hv[8];
        #pragma unroll
        for (int q = 0; q < 8; ++q)
            hv[q] = bf2f(h[(size_t)a[q].x * F_OUT + lane]);
        #pragma unroll
        for (int q = 0; q < 8; ++q) {
            float ww = (u + q < e) ? __int_as_float(a[q].y) * di : 0.f;
            acc += hv[q] * ww;
        }
    }
    acc += bias[lane];
    float m = acc;
    #pragma unroll
    for (int o = 32; o >= 1; o >>= 1) m = fmaxf(m, __shfl_xor(m, o, 64));
    float ex = expf(acc - m);
    float ssum = ex;
    #pragma unroll
    for (int o = 32; o >= 1; o >>= 1) ssum += __shfl_xor(ssum, o, 64);
    outm[(size_t)i * F_OUT + lane] = acc - m - logf(ssum);
}

extern "C" void kernel_launch(void* const* d_in, const int* in_sizes, int n_in,
                              void* d_out, int out_size, void* d_ws, size_t ws_size,
                              hipStream_t stream) {
    const float* x  = (const float*)d_in[0];
    const int*   ei = (const int*)d_in[1];
    const float* W1 = (const float*)d_in[2];
    const float* b1 = (const float*)d_in[3];
    const float* W2 = (const float*)d_in[4];
    const float* b2 = (const float*)d_in[5];
    float* out = (float*)d_out;

    int N = in_sizes[0] / F_IN;   // 50000
    int E = in_sizes[1] / 2;      // 800000
    const int* src = ei;
    const int* dst = ei + E;

    // workspace layout (16B aligned by construction)
    ushort* w1t = (ushort*)d_ws;                        // 256*512
    ushort* w2t = w1t + F_HID * F_IN;                   // 64*256
    ushort* h1  = w2t + F_OUT * F_HID;                  // N*256 bf16
    ushort* a1  = h1 + (size_t)N * F_HID;               // N*256 bf16
    int*    deg = (int*)(a1 + (size_t)N * F_HID);       // N
    float*  dinv = (float*)(deg + N);                   // N
    int*    offs = (int*)(dinv + N);                    // N+1
    int*    cursor = offs + N + 1;                      // N
    int*    bsums  = cursor + N;                        // 256
    int2*   jw = (int2*)(((uintptr_t)(bsums + 256) + 7) & ~(uintptr_t)7);  // E+16
    ushort* h2 = h1;     // alias: h1 dead after agg1

    int nch = (N + 255) / 256;

    hipMemsetAsync(deg, 0, sizeof(int) * N, stream);
    k_deg <<<(E + 255) / 256, 256, 0, stream>>>(dst, deg, E);
    k_scan1<<<nch, 256, 0, stream>>>(deg, offs, bsums, dinv, N);
    k_scan2<<<1, 256, 0, stream>>>(bsums, nch);
    k_scan3<<<nch, 256, 0, stream>>>(offs, bsums, cursor, jw, N, E);
    k_fill<<<(E + 255) / 256, 256, 0, stream>>>(src, dst, cursor, jw, dinv, E);

    // weight transpose-casts (one launch)
    int ntc = F_IN * F_HID + F_HID * F_OUT;
    k_tcast2<<<(ntc + 255) / 256, 256, 0, stream>>>(W1, w1t, W2, w2t);

    // layer 1: fused cast+GEMM (128x128, A prefetch pipeline) + paired-gather aggregate
    k_gemm1<<<dim3(F_HID / 128, (N + 127) / 128), 256, 0, stream>>>(x, w1t, h1, N);
    k_agg1<<<(N + 3) / 4, 256, 0, stream>>>(h1, jw, offs, dinv, b1, a1, N);

    // layer 2: GEMM (BM=128, BN=64) + aggregate + log_softmax
    k_gemm_bf16<4, 1, 2, 4><<<dim3(1, (N + 127) / 128), 256, 0, stream>>>(
        a1, w2t, h2, N, F_HID, F_OUT);
    k_agg2<<<(N + 3) / 4, 256, 0, stream>>>(h2, jw, offs, dinv, b2, out, N);
}

// Round 8
// 260.421 us; speedup vs baseline: 1.0930x; 1.0065x over previous
//
#include <hip/hip_runtime.h>
#include <math.h>

#define F_IN  512
#define F_HID 256
#define F_OUT 64

typedef __attribute__((ext_vector_type(8))) short bf16x8;
typedef __attribute__((ext_vector_type(4))) short bf16x4;
typedef __attribute__((ext_vector_type(4))) float f32x4;

#define GLOBAL_AS __attribute__((address_space(1)))
#define LDS_AS    __attribute__((address_space(3)))

__device__ __forceinline__ void gload_lds16(const ushort* g, ushort* l) {
    __builtin_amdgcn_global_load_lds((const GLOBAL_AS uint32_t*)g,
                                     (LDS_AS uint32_t*)l, 16, 0, 0);
}

__device__ __forceinline__ ushort f2bf(float f) {
    union { float f; uint32_t u; } v; v.f = f;
    uint32_t r = (v.u + 0x7FFFu + ((v.u >> 16) & 1u)) >> 16;
    return (ushort)r;
}

__device__ __forceinline__ float bf2f(ushort u) {
    union { uint32_t u; float f; } v; v.u = ((uint32_t)u) << 16;
    return v.f;
}

// ---------------- degree ----------------
__global__ void k_deg(const int* __restrict__ dst, int* __restrict__ deg, int E) {
    int e = blockIdx.x * 256 + threadIdx.x;
    if (e < E) atomicAdd(&deg[dst[e]], 1);
}

// ---------------- scan level 1 (+ dinv fused) ----------------
__global__ void k_scan1(const int* __restrict__ deg, int* __restrict__ offs,
                        int* __restrict__ bsums, float* __restrict__ dinv, int N) {
    __shared__ int s[256];
    int tid = threadIdx.x;
    int i = blockIdx.x * 256 + tid;
    int v = (i < N) ? deg[i] : 0;
    if (i < N) dinv[i] = rsqrtf((float)(v + 1));   // +1 self loop
    s[tid] = v; __syncthreads();
    for (int d = 1; d < 256; d <<= 1) {
        int t = (tid >= d) ? s[tid - d] : 0;
        __syncthreads();
        s[tid] += t;
        __syncthreads();
    }
    if (i < N) offs[i] = s[tid] - v;
    if (tid == 255) bsums[blockIdx.x] = s[255];
}

__global__ void k_scan2(int* __restrict__ bsums, int n) {
    __shared__ int s[256];
    int tid = threadIdx.x;
    int v = (tid < n) ? bsums[tid] : 0;
    s[tid] = v; __syncthreads();
    for (int d = 1; d < 256; d <<= 1) {
        int t = (tid >= d) ? s[tid - d] : 0;
        __syncthreads();
        s[tid] += t;
        __syncthreads();
    }
    if (tid < n) bsums[tid] = s[tid] - v;
}

__global__ void k_scan3(int* __restrict__ offs, const int* __restrict__ bsums,
                        int* __restrict__ cursor, int2* __restrict__ jw, int N, int E) {
    int i = blockIdx.x * 256 + threadIdx.x;
    if (i < N) {
        int o = offs[i] + bsums[i >> 8];
        offs[i] = o;
        cursor[i] = o;
    }
    if (i == 0) offs[N] = E;
    if (i < 16) jw[E + i] = make_int2(0, 0);   // pad: row 0, weight 0
}

// fill packed (src_index, dinv[src]) per CSR slot
__global__ void k_fill(const int* __restrict__ src, const int* __restrict__ dst,
                       int* __restrict__ cursor, int2* __restrict__ jw,
                       const float* __restrict__ dinv, int E) {
    int e = blockIdx.x * 256 + threadIdx.x;
    if (e < E) {
        int s = src[e];
        int pos = atomicAdd(&cursor[dst[e]], 1);
        jw[pos] = make_int2(s, __float_as_int(dinv[s]));
    }
}

// ---------------- weight transpose-casts (W1 and W2 in one launch) ----------------
__global__ void k_tcast2(const float* __restrict__ W1, ushort* __restrict__ w1t,
                         const float* __restrict__ W2, ushort* __restrict__ w2t) {
    int idx = blockIdx.x * 256 + threadIdx.x;
    const int n1 = F_IN * F_HID;
    if (idx < n1) {
        int n = idx / F_IN, k = idx - n * F_IN;
        w1t[idx] = f2bf(W1[(size_t)k * F_HID + n]);
    } else {
        int t = idx - n1;
        if (t < F_HID * F_OUT) {
            int n = t / F_HID, k = t - n * F_HID;
            w2t[t] = f2bf(W2[(size_t)k * F_OUT + n]);
        }
    }
}

// ---------------- GEMM1: h1[M,256] = bf16( fp32 x[M,512] @ w1t^T ) ----------------
// 128x128 tile, BK=32, 4 waves, 2-phase double-buffered pipeline:
//   iter t: stage B(t+1)+A(t+1) into buf^1, issue A-loads(t+2), compute buf, 1 barrier.
// A: reg-staged fp32->bf16, padded LDS stride 36 (conflict-free frag reads).
// B: global_load_lds with chunk-XOR pre-swizzle (8-way -> 2-way frag-read conflicts).
__global__ __launch_bounds__(256) void k_gemm1(
        const float* __restrict__ A, const ushort* __restrict__ Bt,
        ushort* __restrict__ C, int M) {
    constexpr int K = F_IN, Nc = F_HID, BM = 128, BN = 128, NT = K / 32;
    constexpr int ASTR = 36;
    __shared__ ushort As[2][BM * ASTR];
    __shared__ ushort Bs[2][BN * 32];
    const int tid  = threadIdx.x;
    const int wave = tid >> 6, lane = tid & 63;
    const int wr = wave & 1, wc = wave >> 1;
    const int brow = blockIdx.y * BM, bcol = blockIdx.x * BN;

    f32x4 acc[4][4];
    #pragma unroll
    for (int m = 0; m < 4; ++m)
        #pragma unroll
        for (int n = 0; n < 4; ++n) acc[m][n] = (f32x4){0.f, 0.f, 0.f, 0.f};

    // A stage map: 2 threads per row, 16 fp32 (4x float4) each
    const int arow = tid >> 1;
    const int akh  = (tid & 1) * 16;                 // float (== ushort) offset in row
    int agrow = brow + arow; if (agrow >= M) agrow = M - 1;
    const float4* ap = (const float4*)&A[(size_t)agrow * K + akh];   // step t at ap[t*8 + q]
    // B stage map: 4 threads per row, 16B each, chunk-XOR pre-swizzle (same 64B line)
    const int srow = tid >> 2;                        // 0..63
    const int csrc = (lane & 3) ^ ((lane >> 3) & 3);  // source chunk for this lane's slot
    const ushort* bp0 = &Bt[(size_t)(bcol + srow) * K + csrc * 8];
    const ushort* bp1 = &Bt[(size_t)(bcol + 64 + srow) * K + csrc * 8];

    // fragment read offsets
    const int kqA = (lane >> 4) * 8;                                  // A: unswizzled
    const int kqB = ((lane >> 4) ^ ((lane >> 1) & 3)) * 8;            // B: XOR-swizzled
    const int rA0 = wr * 64 + (lane & 15);
    const int rB0 = wc * 64 + (lane & 15);

    float4 rA[2][4];

    // ---- prologue: A(0)->convert->As[0]; B(0)->Bs[0]; A(1)->regs ----
    #pragma unroll
    for (int q = 0; q < 4; ++q) rA[0][q] = ap[q];
    gload_lds16(bp0, &Bs[0][wave * 512]);
    gload_lds16(bp1, &Bs[0][2048 + wave * 512]);
    {
        bf16x8 c0, c1;
        c0[0] = (short)f2bf(rA[0][0].x); c0[1] = (short)f2bf(rA[0][0].y);
        c0[2] = (short)f2bf(rA[0][0].z); c0[3] = (short)f2bf(rA[0][0].w);
        c0[4] = (short)f2bf(rA[0][1].x); c0[5] = (short)f2bf(rA[0][1].y);
        c0[6] = (short)f2bf(rA[0][1].z); c0[7] = (short)f2bf(rA[0][1].w);
        c1[0] = (short)f2bf(rA[0][2].x); c1[1] = (short)f2bf(rA[0][2].y);
        c1[2] = (short)f2bf(rA[0][2].z); c1[3] = (short)f2bf(rA[0][2].w);
        c1[4] = (short)f2bf(rA[0][3].x); c1[5] = (short)f2bf(rA[0][3].y);
        c1[6] = (short)f2bf(rA[0][3].z); c1[7] = (short)f2bf(rA[0][3].w);
        *(bf16x8*)&As[0][arow * ASTR + akh]     = c0;
        *(bf16x8*)&As[0][arow * ASTR + akh + 8] = c1;
    }
    #pragma unroll
    for (int q = 0; q < 4; ++q) rA[1][q] = ap[8 + q];
    __syncthreads();

    // ---- main loop, fully unrolled (static buffer / reg-set indices) ----
    #pragma unroll
    for (int t = 0; t < NT; ++t) {
        const int b = t & 1;
        if (t + 1 < NT) {
            // stage B(t+1)
            gload_lds16(bp0 + (t + 1) * 32, &Bs[b ^ 1][wave * 512]);
            gload_lds16(bp1 + (t + 1) * 32, &Bs[b ^ 1][2048 + wave * 512]);
            // convert A(t+1) (regs loaded one iter ago) -> As[b^1]
            const float4* r = rA[(t + 1) & 1];
            bf16x8 c0, c1;
            c0[0] = (short)f2bf(r[0].x); c0[1] = (short)f2bf(r[0].y);
            c0[2] = (short)f2bf(r[0].z); c0[3] = (short)f2bf(r[0].w);
            c0[4] = (short)f2bf(r[1].x); c0[5] = (short)f2bf(r[1].y);
            c0[6] = (short)f2bf(r[1].z); c0[7] = (short)f2bf(r[1].w);
            c1[0] = (short)f2bf(r[2].x); c1[1] = (short)f2bf(r[2].y);
            c1[2] = (short)f2bf(r[2].z); c1[3] = (short)f2bf(r[2].w);
            c1[4] = (short)f2bf(r[3].x); c1[5] = (short)f2bf(r[3].y);
            c1[6] = (short)f2bf(r[3].z); c1[7] = (short)f2bf(r[3].w);
            *(bf16x8*)&As[b ^ 1][arow * ASTR + akh]     = c0;
            *(bf16x8*)&As[b ^ 1][arow * ASTR + akh + 8] = c1;
        }
        if (t + 2 < NT) {
            // issue A-loads(t+2) into the reg set consumed above
            #pragma unroll
            for (int q = 0; q < 4; ++q) rA[t & 1][q] = ap[(t + 2) * 8 + q];
        }
        // compute k-step t from buf b
        bf16x8 af[4], bfr[4];
        #pragma unroll
        for (int m = 0; m < 4; ++m)
            af[m] = *(const bf16x8*)&As[b][(rA0 + m * 16) * ASTR + kqA];
        #pragma unroll
        for (int n = 0; n < 4; ++n)
            bfr[n] = *(const bf16x8*)&Bs[b][(rB0 + n * 16) * 32 + kqB];
        #pragma unroll
        for (int m = 0; m < 4; ++m)
            #pragma unroll
            for (int n = 0; n < 4; ++n)
                acc[m][n] = __builtin_amdgcn_mfma_f32_16x16x32_bf16(af[m], bfr[n], acc[m][n], 0, 0, 0);
        if (t + 1 < NT) __syncthreads();
    }

    const int crow0 = brow + wr * 64 + (lane >> 4) * 4;
    const int ccol0 = bcol + wc * 64 + (lane & 15);
    #pragma unroll
    for (int m = 0; m < 4; ++m)
        #pragma unroll
        for (int n = 0; n < 4; ++n)
            #pragma unroll
            for (int j = 0; j < 4; ++j) {
                int row = crow0 + m * 16 + j;
                if (row < M) C[(size_t)row * Nc + ccol0 + n * 16] = f2bf(acc[m][n][j]);
            }
}

// ---------------- bf16 MFMA GEMM2: C[M,64] = A[M,256] @ Bt[64,256]^T (bf16 out) ----------------
template<int WR, int WC, int MR, int NR>
__global__ __launch_bounds__(256) void k_gemm_bf16(
        const ushort* __restrict__ A, const ushort* __restrict__ Bt,
        ushort* __restrict__ C, int M, int K, int Nc) {
    constexpr int BM = WR * MR * 16;
    constexpr int BN = WC * NR * 16;
    __shared__ ushort As[BM * 32];
    __shared__ ushort Bs[BN * 32];
    const int tid  = threadIdx.x;
    const int wave = tid >> 6, lane = tid & 63;
    const int wr = wave % WR, wc = wave / WR;
    const int brow = blockIdx.y * BM, bcol = blockIdx.x * BN;

    f32x4 acc[MR][NR];
    #pragma unroll
    for (int m = 0; m < MR; ++m)
        #pragma unroll
        for (int n = 0; n < NR; ++n) acc[m][n] = (f32x4){0.f, 0.f, 0.f, 0.f};

    const int srow = tid >> 2;
    const int scol = (tid & 3) * 8;
    const int kq  = (lane >> 4) * 8;
    const int rA0 = wr * MR * 16 + (lane & 15);
    const int rB0 = wc * NR * 16 + (lane & 15);

    for (int k0 = 0; k0 < K; k0 += 32) {
        #pragma unroll
        for (int l = 0; l < BM / 64; ++l) {
            int row = brow + l * 64 + srow;
            if (row >= M) row = M - 1;
            gload_lds16(&A[(size_t)row * K + k0 + scol], &As[l * 2048 + wave * 512]);
        }
        #pragma unroll
        for (int l = 0; l < BN / 64; ++l) {
            int row = bcol + l * 64 + srow;
            gload_lds16(&Bt[(size_t)row * K + k0 + scol], &Bs[l * 2048 + wave * 512]);
        }
        __syncthreads();
        bf16x8 af[MR], bfr[NR];
        #pragma unroll
        for (int m = 0; m < MR; ++m)
            af[m] = *(const bf16x8*)&As[(rA0 + m * 16) * 32 + kq];
        #pragma unroll
        for (int n = 0; n < NR; ++n)
            bfr[n] = *(const bf16x8*)&Bs[(rB0 + n * 16) * 32 + kq];
        #pragma unroll
        for (int m = 0; m < MR; ++m)
            #pragma unroll
            for (int n = 0; n < NR; ++n)
                acc[m][n] = __builtin_amdgcn_mfma_f32_16x16x32_bf16(af[m], bfr[n], acc[m][n], 0, 0, 0);
        __syncthreads();
    }

    const int crow0 = brow + wr * MR * 16 + (lane >> 4) * 4;
    const int ccol0 = bcol + wc * NR * 16 + (lane & 15);
    #pragma unroll
    for (int m = 0; m < MR; ++m)
        #pragma unroll
        for (int n = 0; n < NR; ++n)
            #pragma unroll
            for (int j = 0; j < 4; ++j) {
                int row = crow0 + m * 16 + j;
                if (row < M) C[(size_t)row * Nc + ccol0 + n * 16] = f2bf(acc[m][n][j]);
            }
}

// ---------------- layer-1 aggregation: paired-row gathers ----------------
__global__ __launch_bounds__(256) void k_agg1(
        const ushort* __restrict__ h, const int2* __restrict__ jw,
        const int* __restrict__ offs, const float* __restrict__ dinv,
        const float* __restrict__ bias, ushort* __restrict__ outm, int N) {
    int wave = threadIdx.x >> 6, lane = threadIdx.x & 63;
    int i = blockIdx.x * 4 + wave;
    if (i >= N) return;
    int g = lane & 31;        // features g*8 .. g*8+7
    int p = lane >> 5;        // edge parity
    float di = dinv[i];
    float acc[8];
    {
        bf16x8 hv = *(const bf16x8*)&h[(size_t)i * F_HID + g * 8];
        float w = (p == 0) ? di * di : 0.f;     // self loop counted once
        #pragma unroll
        for (int k = 0; k < 8; ++k) acc[k] = bf2f((ushort)hv[k]) * w;
    }
    int s = offs[i], e = offs[i + 1];
    for (int u = s; u < e; u += 12) {
        int2 a[6];
        #pragma unroll
        for (int q = 0; q < 6; ++q) a[q] = jw[u + 2 * q + p];   // overrun -> pad/next-node, masked
        bf16x8 hv[6];
        #pragma unroll
        for (int q = 0; q < 6; ++q)
            hv[q] = *(const bf16x8*)&h[(size_t)a[q].x * F_HID + g * 8];
        #pragma unroll
        for (int q = 0; q < 6; ++q) {
            float ww = (u + 2 * q + p < e) ? __int_as_float(a[q].y) * di : 0.f;
            #pragma unroll
            for (int k = 0; k < 8; ++k) acc[k] += bf2f((ushort)hv[q][k]) * ww;
        }
    }
    #pragma unroll
    for (int k = 0; k < 8; ++k) acc[k] += __shfl_xor(acc[k], 32, 64);
    if (p == 0) {
        float4 b0 = *(const float4*)&bias[g * 8];
        float4 b1 = *(const float4*)&bias[g * 8 + 4];
        bf16x8 o;
        o[0] = (short)f2bf(fmaxf(acc[0] + b0.x, 0.f));
        o[1] = (short)f2bf(fmaxf(acc[1] + b0.y, 0.f));
        o[2] = (short)f2bf(fmaxf(acc[2] + b0.z, 0.f));
        o[3] = (short)f2bf(fmaxf(acc[3] + b0.w, 0.f));
        o[4] = (short)f2bf(fmaxf(acc[4] + b1.x, 0.f));
        o[5] = (short)f2bf(fmaxf(acc[5] + b1.y, 0.f));
        o[6] = (short)f2bf(fmaxf(acc[6] + b1.z, 0.f));
        o[7] = (short)f2bf(fmaxf(acc[7] + b1.w, 0.f));
        *(bf16x8*)&outm[(size_t)i * F_HID + g * 8] = o;
    }
}

// ---------------- layer-2 aggregation + bias + log_softmax: wave per node, 8-unroll ----------------
__global__ __launch_bounds__(256) void k_agg2(
        const ushort* __restrict__ h, const int2* __restrict__ jw,
        const int* __restrict__ offs, const float* __restrict__ dinv,
        const float* __restrict__ bias, float* __restrict__ outm, int N) {
    int wave = threadIdx.x >> 6, lane = threadIdx.x & 63;
    int i = blockIdx.x * 4 + wave;
    if (i >= N) return;
    float di = dinv[i];
    float acc = bf2f(h[(size_t)i * F_OUT + lane]) * di * di;
    int s = offs[i], e = offs[i + 1];
    for (int u = s; u < e; u += 8) {
        int2 a[8];
        #pragma unroll
        for (int q = 0; q < 8; ++q) a[q] = jw[u + q];
        float hv[8];
        #pragma unroll
        for (int q = 0; q < 8; ++q)
            hv[q] = bf2f(h[(size_t)a[q].x * F_OUT + lane]);
        #pragma unroll
        for (int q = 0; q < 8; ++q) {
            float ww = (u + q < e) ? __int_as_float(a[q].y) * di : 0.f;
            acc += hv[q] * ww;
        }
    }
    acc += bias[lane];
    float m = acc;
    #pragma unroll
    for (int o = 32; o >= 1; o >>= 1) m = fmaxf(m, __shfl_xor(m, o, 64));
    float ex = expf(acc - m);
    float ssum = ex;
    #pragma unroll
    for (int o = 32; o >= 1; o >>= 1) ssum += __shfl_xor(ssum, o, 64);
    outm[(size_t)i * F_OUT + lane] = acc - m - logf(ssum);
}

extern "C" void kernel_launch(void* const* d_in, const int* in_sizes, int n_in,
                              void* d_out, int out_size, void* d_ws, size_t ws_size,
                              hipStream_t stream) {
    const float* x  = (const float*)d_in[0];
    const int*   ei = (const int*)d_in[1];
    const float* W1 = (const float*)d_in[2];
    const float* b1 = (const float*)d_in[3];
    const float* W2 = (const float*)d_in[4];
    const float* b2 = (const float*)d_in[5];
    float* out = (float*)d_out;

    int N = in_sizes[0] / F_IN;   // 50000
    int E = in_sizes[1] / 2;      // 800000
    const int* src = ei;
    const int* dst = ei + E;

    // workspace layout (16B aligned by construction)
    ushort* w1t = (ushort*)d_ws;                        // 256*512
    ushort* w2t = w1t + F_HID * F_IN;                   // 64*256
    ushort* h1  = w2t + F_OUT * F_HID;                  // N*256 bf16
    ushort* a1  = h1 + (size_t)N * F_HID;               // N*256 bf16
    int*    deg = (int*)(a1 + (size_t)N * F_HID);       // N
    float*  dinv = (float*)(deg + N);                   // N
    int*    offs = (int*)(dinv + N);                    // N+1
    int*    cursor = offs + N + 1;                      // N
    int*    bsums  = cursor + N;                        // 256
    int2*   jw = (int2*)(((uintptr_t)(bsums + 256) + 7) & ~(uintptr_t)7);  // E+16
    ushort* h2 = h1;     // alias: h1 dead after agg1

    int nch = (N + 255) / 256;

    hipMemsetAsync(deg, 0, sizeof(int) * N, stream);
    k_deg <<<(E + 255) / 256, 256, 0, stream>>>(dst, deg, E);
    k_scan1<<<nch, 256, 0, stream>>>(deg, offs, bsums, dinv, N);
    k_scan2<<<1, 256, 0, stream>>>(bsums, nch);
    k_scan3<<<nch, 256, 0, stream>>>(offs, bsums, cursor, jw, N, E);
    k_fill<<<(E + 255) / 256, 256, 0, stream>>>(src, dst, cursor, jw, dinv, E);

    // weight transpose-casts (one launch)
    int ntc = F_IN * F_HID + F_HID * F_OUT;
    k_tcast2<<<(ntc + 255) / 256, 256, 0, stream>>>(W1, w1t, W2, w2t);

    // layer 1: fused cast+GEMM (2-phase pipelined) + paired-gather aggregate
    k_gemm1<<<dim3(F_HID / 128, (N + 127) / 128), 256, 0, stream>>>(x, w1t, h1, N);
    k_agg1<<<(N + 3) / 4, 256, 0, stream>>>(h1, jw, offs, dinv, b1, a1, N);

    // layer 2: GEMM (BM=128, BN=64) + aggregate + log_softmax
    k_gemm_bf16<4, 1, 2, 4><<<dim3(1, (N + 127) / 128), 256, 0, stream>>>(
        a1, w2t, h2, N, F_HID, F_OUT);
    k_agg2<<<(N + 3) / 4, 256, 0, stream>>>(h2, jw, offs, dinv, b2, out, N);
}

// Round 9
// 254.112 us; speedup vs baseline: 1.1201x; 1.0248x over previous
//
#include <hip/hip_runtime.h>
#include <math.h>

#define F_IN  512
#define F_HID 256
#define F_OUT 64

typedef __attribute__((ext_vector_type(8))) short bf16x8;
typedef __attribute__((ext_vector_type(4))) short bf16x4;
typedef __attribute__((ext_vector_type(4))) float f32x4;

#define GLOBAL_AS __attribute__((address_space(1)))
#define LDS_AS    __attribute__((address_space(3)))

__device__ __forceinline__ void gload_lds16(const ushort* g, ushort* l) {
    __builtin_amdgcn_global_load_lds((const GLOBAL_AS uint32_t*)g,
                                     (LDS_AS uint32_t*)l, 16, 0, 0);
}

__device__ __forceinline__ ushort f2bf(float f) {
    union { float f; uint32_t u; } v; v.f = f;
    uint32_t r = (v.u + 0x7FFFu + ((v.u >> 16) & 1u)) >> 16;
    return (ushort)r;
}

__device__ __forceinline__ float bf2f(ushort u) {
    union { uint32_t u; float f; } v; v.u = ((uint32_t)u) << 16;
    return v.f;
}

// ---------------- degree ----------------
__global__ void k_deg(const int* __restrict__ dst, int* __restrict__ deg, int E) {
    int e = blockIdx.x * 256 + threadIdx.x;
    if (e < E) atomicAdd(&deg[dst[e]], 1);
}

// ---------------- scan level 1 (+ dinv fused) ----------------
__global__ void k_scan1(const int* __restrict__ deg, int* __restrict__ offs,
                        int* __restrict__ bsums, float* __restrict__ dinv, int N) {
    __shared__ int s[256];
    int tid = threadIdx.x;
    int i = blockIdx.x * 256 + tid;
    int v = (i < N) ? deg[i] : 0;
    if (i < N) dinv[i] = rsqrtf((float)(v + 1));   // +1 self loop
    s[tid] = v; __syncthreads();
    for (int d = 1; d < 256; d <<= 1) {
        int t = (tid >= d) ? s[tid - d] : 0;
        __syncthreads();
        s[tid] += t;
        __syncthreads();
    }
    if (i < N) offs[i] = s[tid] - v;
    if (tid == 255) bsums[blockIdx.x] = s[255];
}

__global__ void k_scan2(int* __restrict__ bsums, int n) {
    __shared__ int s[256];
    int tid = threadIdx.x;
    int v = (tid < n) ? bsums[tid] : 0;
    s[tid] = v; __syncthreads();
    for (int d = 1; d < 256; d <<= 1) {
        int t = (tid >= d) ? s[tid - d] : 0;
        __syncthreads();
        s[tid] += t;
        __syncthreads();
    }
    if (tid < n) bsums[tid] = s[tid] - v;
}

__global__ void k_scan3(int* __restrict__ offs, const int* __restrict__ bsums,
                        int* __restrict__ cursor, int2* __restrict__ jw, int N, int E) {
    int i = blockIdx.x * 256 + threadIdx.x;
    if (i < N) {
        int o = offs[i] + bsums[i >> 8];
        offs[i] = o;
        cursor[i] = o;
    }
    if (i == 0) offs[N] = E;
    if (i < 16) jw[E + i] = make_int2(0, 0);   // pad: row 0, weight 0
}

// fill packed (src_index, dinv[src]) per CSR slot
__global__ void k_fill(const int* __restrict__ src, const int* __restrict__ dst,
                       int* __restrict__ cursor, int2* __restrict__ jw,
                       const float* __restrict__ dinv, int E) {
    int e = blockIdx.x * 256 + threadIdx.x;
    if (e < E) {
        int s = src[e];
        int pos = atomicAdd(&cursor[dst[e]], 1);
        jw[pos] = make_int2(s, __float_as_int(dinv[s]));
    }
}

// ---------------- weight transpose-casts (W1 and W2 in one launch) ----------------
__global__ void k_tcast2(const float* __restrict__ W1, ushort* __restrict__ w1t,
                         const float* __restrict__ W2, ushort* __restrict__ w2t) {
    int idx = blockIdx.x * 256 + threadIdx.x;
    const int n1 = F_IN * F_HID;
    if (idx < n1) {
        int n = idx / F_IN, k = idx - n * F_IN;
        w1t[idx] = f2bf(W1[(size_t)k * F_HID + n]);
    } else {
        int t = idx - n1;
        if (t < F_HID * F_OUT) {
            int n = t / F_HID, k = t - n * F_HID;
            w2t[t] = f2bf(W2[(size_t)k * F_OUT + n]);
        }
    }
}

// ---------------- GEMM1: h1[M,256] = bf16( fp32 x[M,512] @ w1t^T ) ----------------
// BM=64 x BN=128 tile -> 1564 blocks (2x r8's grid). 4 waves in 2x2, MR=2 NR=4
// (acc = 32 VGPR). Double-buffered; B chunk-XOR swizzled; one barrier/iter.
__global__ __launch_bounds__(256) void k_gemm1(
        const float* __restrict__ A, const ushort* __restrict__ Bt,
        ushort* __restrict__ C, int M) {
    constexpr int K = F_IN, Nc = F_HID, BM = 64, BN = 128, NT = K / 32;
    constexpr int ASTR = 36;
    __shared__ ushort As[2][BM * ASTR];
    __shared__ ushort Bs[2][BN * 32];
    const int tid  = threadIdx.x;
    const int wave = tid >> 6, lane = tid & 63;
    const int wr = wave & 1, wc = wave >> 1;       // 2x2 wave grid
    const int brow = blockIdx.y * BM, bcol = blockIdx.x * BN;

    f32x4 acc[2][4];
    #pragma unroll
    for (int m = 0; m < 2; ++m)
        #pragma unroll
        for (int n = 0; n < 4; ++n) acc[m][n] = (f32x4){0.f, 0.f, 0.f, 0.f};

    // A stage: 4 thr/row, 8 fp32 (2 float4) each; rows 0..63
    const int arow = tid >> 2;
    const int akc  = (tid & 3) * 8;
    int agrow = brow + arow; if (agrow >= M) agrow = M - 1;
    const float4* ap = (const float4*)&A[(size_t)agrow * K + akc];   // step t at ap[t*8+q]
    // B stage: 4 thr/row over two 64-row groups; chunk-XOR pre-swizzled source
    const int csrc = (tid & 3) ^ ((tid >> 3) & 3);
    const ushort* bp0 = &Bt[(size_t)(bcol + (tid >> 2)) * K + csrc * 8];
    const ushort* bp1 = &Bt[(size_t)(bcol + 64 + (tid >> 2)) * K + csrc * 8];

    const int kqA = (lane >> 4) * 8;
    const int kqB = ((lane >> 4) ^ ((lane >> 1) & 3)) * 8;   // undo store swizzle
    const int rA0 = wr * 32 + (lane & 15);
    const int rB0 = wc * 64 + (lane & 15);

    // ---- prologue: stage t=0 into buf 0 ----
    {
        float4 v0 = ap[0], v1 = ap[1];
        bf16x8 c0;
        c0[0] = (short)f2bf(v0.x); c0[1] = (short)f2bf(v0.y);
        c0[2] = (short)f2bf(v0.z); c0[3] = (short)f2bf(v0.w);
        c0[4] = (short)f2bf(v1.x); c0[5] = (short)f2bf(v1.y);
        c0[6] = (short)f2bf(v1.z); c0[7] = (short)f2bf(v1.w);
        *(bf16x8*)&As[0][arow * ASTR + akc] = c0;
        gload_lds16(bp0, &Bs[0][wave * 512]);
        gload_lds16(bp1, &Bs[0][2048 + wave * 512]);
    }
    __syncthreads();

    #pragma unroll
    for (int t = 0; t < NT; ++t) {
        const int b = t & 1;
        if (t + 1 < NT) {
            // stage k-step t+1 into buf b^1 (overlaps compute of t)
            gload_lds16(bp0 + (t + 1) * 32, &Bs[b ^ 1][wave * 512]);
            gload_lds16(bp1 + (t + 1) * 32, &Bs[b ^ 1][2048 + wave * 512]);
            float4 v0 = ap[(t + 1) * 8], v1 = ap[(t + 1) * 8 + 1];
            bf16x8 c0;
            c0[0] = (short)f2bf(v0.x); c0[1] = (short)f2bf(v0.y);
            c0[2] = (short)f2bf(v0.z); c0[3] = (short)f2bf(v0.w);
            c0[4] = (short)f2bf(v1.x); c0[5] = (short)f2bf(v1.y);
            c0[6] = (short)f2bf(v1.z); c0[7] = (short)f2bf(v1.w);
            *(bf16x8*)&As[b ^ 1][arow * ASTR + akc] = c0;
        }
        // compute k-step t from buf b
        bf16x8 af[2], bfr[4];
        #pragma unroll
        for (int m = 0; m < 2; ++m)
            af[m] = *(const bf16x8*)&As[b][(rA0 + m * 16) * ASTR + kqA];
        #pragma unroll
        for (int n = 0; n < 4; ++n)
            bfr[n] = *(const bf16x8*)&Bs[b][(rB0 + n * 16) * 32 + kqB];
        #pragma unroll
        for (int m = 0; m < 2; ++m)
            #pragma unroll
            for (int n = 0; n < 4; ++n)
                acc[m][n] = __builtin_amdgcn_mfma_f32_16x16x32_bf16(af[m], bfr[n], acc[m][n], 0, 0, 0);
        if (t + 1 < NT) __syncthreads();
    }

    const int crow0 = brow + wr * 32 + (lane >> 4) * 4;
    const int ccol0 = bcol + wc * 64 + (lane & 15);
    #pragma unroll
    for (int m = 0; m < 2; ++m)
        #pragma unroll
        for (int n = 0; n < 4; ++n)
            #pragma unroll
            for (int j = 0; j < 4; ++j) {
                int row = crow0 + m * 16 + j;
                if (row < M) C[(size_t)row * Nc + ccol0 + n * 16] = f2bf(acc[m][n][j]);
            }
}

// ---------------- bf16 MFMA GEMM2: C[M,Nc] = A[M,K] @ Bt[Nc,K]^T (bf16 out) ----------------
template<int WR, int WC, int MR, int NR>
__global__ __launch_bounds__(256) void k_gemm_bf16(
        const ushort* __restrict__ A, const ushort* __restrict__ Bt,
        ushort* __restrict__ C, int M, int K, int Nc) {
    constexpr int BM = WR * MR * 16;
    constexpr int BN = WC * NR * 16;
    __shared__ ushort As[BM * 32];
    __shared__ ushort Bs[BN * 32];
    const int tid  = threadIdx.x;
    const int wave = tid >> 6, lane = tid & 63;
    const int wr = wave % WR, wc = wave / WR;
    const int brow = blockIdx.y * BM, bcol = blockIdx.x * BN;

    f32x4 acc[MR][NR];
    #pragma unroll
    for (int m = 0; m < MR; ++m)
        #pragma unroll
        for (int n = 0; n < NR; ++n) acc[m][n] = (f32x4){0.f, 0.f, 0.f, 0.f};

    const int srow = tid >> 2;
    const int scol = (tid & 3) * 8;
    const int kq  = (lane >> 4) * 8;
    const int rA0 = wr * MR * 16 + (lane & 15);
    const int rB0 = wc * NR * 16 + (lane & 15);

    for (int k0 = 0; k0 < K; k0 += 32) {
        #pragma unroll
        for (int l = 0; l < BM / 64; ++l) {
            int row = brow + l * 64 + srow;
            if (row >= M) row = M - 1;
            gload_lds16(&A[(size_t)row * K + k0 + scol], &As[l * 2048 + wave * 512]);
        }
        #pragma unroll
        for (int l = 0; l < BN / 64; ++l) {
            int row = bcol + l * 64 + srow;
            gload_lds16(&Bt[(size_t)row * K + k0 + scol], &Bs[l * 2048 + wave * 512]);
        }
        __syncthreads();
        bf16x8 af[MR], bfr[NR];
        #pragma unroll
        for (int m = 0; m < MR; ++m)
            af[m] = *(const bf16x8*)&As[(rA0 + m * 16) * 32 + kq];
        #pragma unroll
        for (int n = 0; n < NR; ++n)
            bfr[n] = *(const bf16x8*)&Bs[(rB0 + n * 16) * 32 + kq];
        #pragma unroll
        for (int m = 0; m < MR; ++m)
            #pragma unroll
            for (int n = 0; n < NR; ++n)
                acc[m][n] = __builtin_amdgcn_mfma_f32_16x16x32_bf16(af[m], bfr[n], acc[m][n], 0, 0, 0);
        __syncthreads();
    }

    const int crow0 = brow + wr * MR * 16 + (lane >> 4) * 4;
    const int ccol0 = bcol + wc * NR * 16 + (lane & 15);
    #pragma unroll
    for (int m = 0; m < MR; ++m)
        #pragma unroll
        for (int n = 0; n < NR; ++n)
            #pragma unroll
            for (int j = 0; j < 4; ++j) {
                int row = crow0 + m * 16 + j;
                if (row < M) C[(size_t)row * Nc + ccol0 + n * 16] = f2bf(acc[m][n][j]);
            }
}

// ---------------- layer-1 aggregation: paired-row gathers ----------------
__global__ __launch_bounds__(256) void k_agg1(
        const ushort* __restrict__ h, const int2* __restrict__ jw,
        const int* __restrict__ offs, const float* __restrict__ dinv,
        const float* __restrict__ bias, ushort* __restrict__ outm, int N) {
    int wave = threadIdx.x >> 6, lane = threadIdx.x & 63;
    int i = blockIdx.x * 4 + wave;
    if (i >= N) return;
    int g = lane & 31;        // features g*8 .. g*8+7
    int p = lane >> 5;        // edge parity
    float di = dinv[i];
    float acc[8];
    {
        bf16x8 hv = *(const bf16x8*)&h[(size_t)i * F_HID + g * 8];
        float w = (p == 0) ? di * di : 0.f;     // self loop counted once
        #pragma unroll
        for (int k = 0; k < 8; ++k) acc[k] = bf2f((ushort)hv[k]) * w;
    }
    int s = offs[i], e = offs[i + 1];
    for (int u = s; u < e; u += 12) {
        int2 a[6];
        #pragma unroll
        for (int q = 0; q < 6; ++q) a[q] = jw[u + 2 * q + p];   // overrun -> pad/next-node, masked
        bf16x8 hv[6];
        #pragma unroll
        for (int q = 0; q < 6; ++q)
            hv[q] = *(const bf16x8*)&h[(size_t)a[q].x * F_HID + g * 8];
        #pragma unroll
        for (int q = 0; q < 6; ++q) {
            float ww = (u + 2 * q + p < e) ? __int_as_float(a[q].y) * di : 0.f;
            #pragma unroll
            for (int k = 0; k < 8; ++k) acc[k] += bf2f((ushort)hv[q][k]) * ww;
        }
    }
    #pragma unroll
    for (int k = 0; k < 8; ++k) acc[k] += __shfl_xor(acc[k], 32, 64);
    if (p == 0) {
        float4 b0 = *(const float4*)&bias[g * 8];
        float4 b1 = *(const float4*)&bias[g * 8 + 4];
        bf16x8 o;
        o[0] = (short)f2bf(fmaxf(acc[0] + b0.x, 0.f));
        o[1] = (short)f2bf(fmaxf(acc[1] + b0.y, 0.f));
        o[2] = (short)f2bf(fmaxf(acc[2] + b0.z, 0.f));
        o[3] = (short)f2bf(fmaxf(acc[3] + b0.w, 0.f));
        o[4] = (short)f2bf(fmaxf(acc[4] + b1.x, 0.f));
        o[5] = (short)f2bf(fmaxf(acc[5] + b1.y, 0.f));
        o[6] = (short)f2bf(fmaxf(acc[6] + b1.z, 0.f));
        o[7] = (short)f2bf(fmaxf(acc[7] + b1.w, 0.f));
        *(bf16x8*)&outm[(size_t)i * F_HID + g * 8] = o;
    }
}

// ---------------- layer-2 aggregation + bias + log_softmax: wave per node, 8-unroll ----------------
__global__ __launch_bounds__(256) void k_agg2(
        const ushort* __restrict__ h, const int2* __restrict__ jw,
        const int* __restrict__ offs, const float* __restrict__ dinv,
        const float* __restrict__ bias, float* __restrict__ outm, int N) {
    int wave = threadIdx.x >> 6, lane = threadIdx.x & 63;
    int i = blockIdx.x * 4 + wave;
    if (i >= N) return;
    float di = dinv[i];
    float acc = bf2f(h[(size_t)i * F_OUT + lane]) * di * di;
    int s = offs[i], e = offs[i + 1];
    for (int u = s; u < e; u += 8) {
        int2 a[8];
        #pragma unroll
        for (int q = 0; q < 8; ++q) a[q] = jw[u + q];
        float hv[8];
        #pragma unroll
        for (int q = 0; q < 8; ++q)
            hv[q] = bf2f(h[(size_t)a[q].x * F_OUT + lane]);
        #pragma unroll
        for (int q = 0; q < 8; ++q) {
            float ww = (u + q < e) ? __int_as_float(a[q].y) * di : 0.f;
            acc += hv[q] * ww;
        }
    }
    acc += bias[lane];
    float m = acc;
    #pragma unroll
    for (int o = 32; o >= 1; o >>= 1) m = fmaxf(m, __shfl_xor(m, o, 64));
    float ex = expf(acc - m);
    float ssum = ex;
    #pragma unroll
    for (int o = 32; o >= 1; o >>= 1) ssum += __shfl_xor(ssum, o, 64);
    outm[(size_t)i * F_OUT + lane] = acc - m - logf(ssum);
}

extern "C" void kernel_launch(void* const* d_in, const int* in_sizes, int n_in,
                              void* d_out, int out_size, void* d_ws, size_t ws_size,
                              hipStream_t stream) {
    const float* x  = (const float*)d_in[0];
    const int*   ei = (const int*)d_in[1];
    const float* W1 = (const float*)d_in[2];
    const float* b1 = (const float*)d_in[3];
    const float* W2 = (const float*)d_in[4];
    const float* b2 = (const float*)d_in[5];
    float* out = (float*)d_out;

    int N = in_sizes[0] / F_IN;   // 50000
    int E = in_sizes[1] / 2;      // 800000
    const int* src = ei;
    const int* dst = ei + E;

    // workspace layout (16B aligned by construction)
    ushort* w1t = (ushort*)d_ws;                        // 256*512
    ushort* w2t = w1t + F_HID * F_IN;                   // 64*256
    ushort* h1  = w2t + F_OUT * F_HID;                  // N*256 bf16
    ushort* a1  = h1 + (size_t)N * F_HID;               // N*256 bf16
    int*    deg = (int*)(a1 + (size_t)N * F_HID);       // N
    float*  dinv = (float*)(deg + N);                   // N
    int*    offs = (int*)(dinv + N);                    // N+1
    int*    cursor = offs + N + 1;                      // N
    int*    bsums  = cursor + N;                        // 256
    int2*   jw = (int2*)(((uintptr_t)(bsums + 256) + 7) & ~(uintptr_t)7);  // E+16
    ushort* h2 = h1;     // alias: h1 dead after agg1

    int nch = (N + 255) / 256;

    hipMemsetAsync(deg, 0, sizeof(int) * N, stream);
    k_deg <<<(E + 255) / 256, 256, 0, stream>>>(dst, deg, E);
    k_scan1<<<nch, 256, 0, stream>>>(deg, offs, bsums, dinv, N);
    k_scan2<<<1, 256, 0, stream>>>(bsums, nch);
    k_scan3<<<nch, 256, 0, stream>>>(offs, bsums, cursor, jw, N, E);
    k_fill<<<(E + 255) / 256, 256, 0, stream>>>(src, dst, cursor, jw, dinv, E);

    // weight transpose-casts (one launch)
    int ntc = F_IN * F_HID + F_HID * F_OUT;
    k_tcast2<<<(ntc + 255) / 256, 256, 0, stream>>>(W1, w1t, W2, w2t);

    // layer 1: fused cast+GEMM (64x128 tile, 1564 blocks) + paired-gather aggregate
    k_gemm1<<<dim3(F_HID / 128, (N + 63) / 64), 256, 0, stream>>>(x, w1t, h1, N);
    k_agg1<<<(N + 3) / 4, 256, 0, stream>>>(h1, jw, offs, dinv, b1, a1, N);

    // layer 2: GEMM (64x64 tile, 782 blocks) + aggregate + log_softmax
    k_gemm_bf16<4, 1, 1, 4><<<dim3(1, (N + 63) / 64), 256, 0, stream>>>(
        a1, w2t, h2, N, F_HID, F_OUT);
    k_agg2<<<(N + 3) / 4, 256, 0, stream>>>(h2, jw, offs, dinv, b2, out, N);
}